// Round 4
// baseline (834.682 us; speedup 1.0000x reference)
//
#include <hip/hip_runtime.h>
#include <hip/hip_bf16.h>
#include <stdint.h>

#define NT   1280
#define EDIM 1024
#define G    2
#define C    512
#define D    64
#define WA   70
#define GC   1024            // G*C
#define O3W  71680           // G*C*WA

// ---------------- JAX threefry2x32 (exact port) ----------------
__device__ __forceinline__ uint32_t rotl32(uint32_t v, int r) {
  return (v << r) | (v >> (32 - r));
}

__device__ __forceinline__ void threefry2x32(uint32_t k0, uint32_t k1,
                                             uint32_t& x0, uint32_t& x1) {
  const uint32_t ks2 = k0 ^ k1 ^ 0x1BD11BDAu;
  x0 += k0; x1 += k1;
#define TF_R(r) { x0 += x1; x1 = rotl32(x1, (r)); x1 ^= x0; }
  TF_R(13) TF_R(15) TF_R(26) TF_R(6)
  x0 += k1;  x1 += ks2 + 1u;
  TF_R(17) TF_R(29) TF_R(16) TF_R(24)
  x0 += ks2; x1 += k0 + 2u;
  TF_R(13) TF_R(15) TF_R(26) TF_R(6)
  x0 += k0;  x1 += k1 + 3u;
  TF_R(17) TF_R(29) TF_R(16) TF_R(24)
  x0 += k1;  x1 += ks2 + 4u;
  TF_R(13) TF_R(15) TF_R(26) TF_R(6)
  x0 += ks2; x1 += k0 + 5u;
#undef TF_R
}

// gumbel for flat index into (NT,G,C), key=(0,42),
// jax_threefry_partitionable=True semantics (default since JAX 0.4.30):
// counter = uint64 idx -> (hi=0, lo=idx); 32-bit bits = out_x0 ^ out_x1.
__device__ __forceinline__ float jax_gumbel(uint32_t idx) {
  uint32_t x0 = 0u, x1 = idx;
  threefry2x32(0u, 42u, x0, x1);
  uint32_t bits = x0 ^ x1;
  float u = __uint_as_float((bits >> 9) | 0x3F800000u) - 1.0f;
  u = fmaxf(u, 1.17549435e-38f);         // jax uniform: max(tiny, u)
  return -logf(-logf(u));
}

// ---------------- f32 tiled GEMM: C = act(A@B + bias) ----------------
// A: MxK row-major, B: KxN row-major, bias: N. BM=BN=64, BK=16, 256 thr, 4x4/thr.
template<bool RELU>
__global__ __launch_bounds__(256) void gemm_bias(
    const float* __restrict__ A, const float* __restrict__ B,
    const float* __restrict__ bias, float* __restrict__ Cout,
    int M, int N, int K) {
  __shared__ float As[16][64];   // [k][m]
  __shared__ float Bs[16][64];   // [k][n]
  const int tid = threadIdx.x;
  const int row0 = blockIdx.y * 64, col0 = blockIdx.x * 64;
  const int tx = tid & 15, ty = tid >> 4;
  const int arow = tid >> 2, acol4 = (tid & 3) * 4;
  const int brow = tid >> 4, bcol4 = (tid & 15) * 4;

  float acc[4][4] = {};
  for (int k0 = 0; k0 < K; k0 += 16) {
    float4 av = *(const float4*)&A[(size_t)(row0 + arow) * K + k0 + acol4];
    As[acol4 + 0][arow] = av.x; As[acol4 + 1][arow] = av.y;
    As[acol4 + 2][arow] = av.z; As[acol4 + 3][arow] = av.w;
    float4 bv = *(const float4*)&B[(size_t)(k0 + brow) * N + col0 + bcol4];
    *(float4*)&Bs[brow][bcol4] = bv;
    __syncthreads();
#pragma unroll
    for (int kk = 0; kk < 16; ++kk) {
      float4 a4 = *(const float4*)&As[kk][ty * 4];
      float4 b4 = *(const float4*)&Bs[kk][tx * 4];
      float a[4] = {a4.x, a4.y, a4.z, a4.w};
      float b[4] = {b4.x, b4.y, b4.z, b4.w};
#pragma unroll
      for (int i = 0; i < 4; ++i)
#pragma unroll
        for (int j = 0; j < 4; ++j)
          acc[i][j] = fmaf(a[i], b[j], acc[i][j]);
    }
    __syncthreads();
  }
#pragma unroll
  for (int i = 0; i < 4; ++i) {
    int r = row0 + ty * 4 + i;
#pragma unroll
    for (int j = 0; j < 4; ++j) {
      int c = col0 + tx * 4 + j;
      float v = acc[i][j] + bias[c];
      if (RELU) v = fmaxf(v, 0.0f);
      Cout[(size_t)r * N + c] = v;
    }
  }
}

// ---------------- categorical sampling (one wave per (t,g)) ----------------
__global__ __launch_bounds__(256) void sample_kernel(
    const float* __restrict__ logits,   // (NT, GC)
    int* __restrict__ centers) {        // (NT*G)
  const int wid = (int)((blockIdx.x * blockDim.x + threadIdx.x) >> 6); // t*G+g
  const int lane = threadIdx.x & 63;
  if (wid >= NT * G) return;
  const float* lrow = logits + (size_t)wid * C;   // t*1024 + g*512 == wid*512
  float bestv = -INFINITY; int bestc = 0;
  for (int i = 0; i < 8; ++i) {
    int c = lane + 64 * i;
    float v = jax_gumbel((uint32_t)(wid * C + c)) + lrow[c];
    if (v > bestv) { bestv = v; bestc = c; }   // increasing c => strict '>' keeps lowest
  }
  for (int off = 32; off > 0; off >>= 1) {
    float ov = __shfl_xor(bestv, off);
    int   oc = __shfl_xor(bestc, off);
    if (ov > bestv || (ov == bestv && oc < bestc)) { bestv = ov; bestc = oc; }
  }
  if (lane == 0) centers[wid] = bestc;
}

// ---------------- per-token: O3 gather-GEMM, decode, a_hat, loss partials ----
__global__ __launch_bounds__(128) void token_kernel(
    const float* __restrict__ HO2,      // (NT,1024)
    const float* __restrict__ O3,       // (1024, O3W)
    const float* __restrict__ ob3,      // (O3W)
    const float* __restrict__ logits,   // (NT, GC)
    const int*   __restrict__ centers,  // (NT*G)
    const int*   __restrict__ bins,     // (NT*G)
    const float* __restrict__ codebook, // (G,C,D)
    const float* __restrict__ Wd,       // (128,70)
    const float* __restrict__ bd,       // (70)
    const float* __restrict__ action,   // (NT,70)
    float* __restrict__ a_hat,          // (NT,70) -> d_out
    float* __restrict__ off_partial,    // (NT)
    float* __restrict__ focal_partial) {// (2*NT), [g*NT+t]
  const int t = blockIdx.x;
  const int tid = threadIdx.x;
  const int lane = tid & 63;
  const int g = tid >> 6;               // wave id = group

  __shared__ float h[1024];
  __shared__ float dec_in[128];
  __shared__ float og[2][WA];
  __shared__ float absdiff[WA];

  { // stage HO2 row
    const float4* src = (const float4*)(HO2 + (size_t)t * 1024);
    float4* dst = (float4*)h;
    for (int i = tid; i < 256; i += 128) dst[i] = src[i];
  }
  const int c = centers[t * G + g];
  dec_in[tid] = codebook[((size_t)(g * C + c)) * D + lane];   // 128 vals
  __syncthreads();

  // gathered offsets for group g: og[g][a] = sum_k h[k]*O3[k, base+a] + ob3[base+a]
  const size_t base = (size_t)(g * C + c) * WA;
  const float* ocol = O3 + base;
  float acc0 = 0.0f, acc1 = 0.0f;
#pragma unroll 4
  for (int k = 0; k < 1024; ++k) {
    float hk = h[k];
    acc0 = fmaf(hk, ocol[(size_t)k * O3W + lane], acc0);
    if (lane < WA - 64) acc1 = fmaf(hk, ocol[(size_t)k * O3W + 64 + lane], acc1);
  }
  acc0 += ob3[base + lane];
  og[g][lane] = acc0;
  if (lane < WA - 64) og[g][64 + lane] = acc1 + ob3[base + 64 + lane];
  __syncthreads();

  // decode + a_hat + |action - a_hat|
  if (tid < WA) {
    float dv = bd[tid];
#pragma unroll 8
    for (int j = 0; j < 128; ++j) dv = fmaf(dec_in[j], Wd[j * WA + tid], dv);
    float ah = dv + og[0][tid] + og[1][tid];
    a_hat[(size_t)t * WA + tid] = ah;
    absdiff[tid] = fabsf(action[(size_t)t * WA + tid] - ah);
  }
  __syncthreads();
  if (tid == 0) {
    float s = 0.0f;
    for (int a = 0; a < WA; ++a) s += absdiff[a];
    off_partial[t] = s;
  }

  // focal partial for group g (wave-wide over 512 logits)
  const float* lrow = logits + (size_t)t * GC + g * C;
  float lv[8], mx = -INFINITY;
#pragma unroll
  for (int i = 0; i < 8; ++i) { lv[i] = lrow[lane + 64 * i]; mx = fmaxf(mx, lv[i]); }
  for (int off = 32; off > 0; off >>= 1) mx = fmaxf(mx, __shfl_xor(mx, off));
  float se = 0.0f;
#pragma unroll
  for (int i = 0; i < 8; ++i) se += expf(lv[i] - mx);
  for (int off = 32; off > 0; off >>= 1) se += __shfl_xor(se, off);
  if (lane == 0) {
    int target = bins[t * G + g];
    float logpt = lrow[target] - mx - logf(se);
    float pt = expf(logpt);
    float om = 1.0f - pt;
    focal_partial[g * NT + t] = -om * om * logpt;
  }
}

// ---------------- final deterministic reduction ----------------
__global__ __launch_bounds__(256) void final_reduce(
    const float* __restrict__ off_partial,
    const float* __restrict__ focal_partial,
    float* __restrict__ out_loss) {
  const int tid = threadIdx.x;
  double s_off = 0.0, s_f0 = 0.0, s_f1 = 0.0;
  for (int t = tid; t < NT; t += 256) {
    s_off += (double)off_partial[t];
    s_f0  += (double)focal_partial[t];
    s_f1  += (double)focal_partial[NT + t];
  }
  __shared__ double sh0[256], sh1[256], sh2[256];
  sh0[tid] = s_off; sh1[tid] = s_f0; sh2[tid] = s_f1;
  __syncthreads();
  for (int s = 128; s > 0; s >>= 1) {
    if (tid < s) { sh0[tid] += sh0[tid + s]; sh1[tid] += sh1[tid + s]; sh2[tid] += sh2[tid + s]; }
    __syncthreads();
  }
  if (tid == 0) {
    double offset_loss = sh0[0] / (double)(NT * WA);
    double cbet = 5.0 * (sh1[0] / (double)NT) + 0.5 * (sh2[0] / (double)NT);
    out_loss[0] = (float)(cbet + 100.0 * offset_loss);
  }
}

// ---------------- launch ----------------
extern "C" void kernel_launch(void* const* d_in, const int* in_sizes, int n_in,
                              void* d_out, int out_size, void* d_ws, size_t ws_size,
                              hipStream_t stream) {
  const float* X       = (const float*)d_in[0];
  const float* action  = (const float*)d_in[1];
  const int*   bins    = (const int*)  d_in[2];
  const float* W1 = (const float*)d_in[3];  const float* b1  = (const float*)d_in[4];
  const float* W2 = (const float*)d_in[5];  const float* b2  = (const float*)d_in[6];
  const float* W3 = (const float*)d_in[7];  const float* b3  = (const float*)d_in[8];
  const float* O1 = (const float*)d_in[9];  const float* ob1 = (const float*)d_in[10];
  const float* O2 = (const float*)d_in[11]; const float* ob2 = (const float*)d_in[12];
  const float* O3 = (const float*)d_in[13]; const float* ob3 = (const float*)d_in[14];
  const float* codebook = (const float*)d_in[15];
  const float* Wd = (const float*)d_in[16]; const float* bd  = (const float*)d_in[17];
  float* out = (float*)d_out;

  // workspace layout (~15.8 MB)
  float* H1  = (float*)d_ws;            // NT*1024   (H1, later HO1)
  float* H2  = H1 + (size_t)NT * 1024;  // NT*1024   (H2, later HO2)
  float* LOG = H2 + (size_t)NT * 1024;  // NT*1024
  int*   centers       = (int*)(LOG + (size_t)NT * 1024);
  float* off_partial   = (float*)(centers + NT * G);
  float* focal_partial = off_partial + NT;

  dim3 blk(256);
  dim3 grd(GC / 64, NT / 64);   // (16, 20)

  // logits MLP
  gemm_bias<true ><<<grd, blk, 0, stream>>>(X,  W1, b1, H1,  NT, 1024, EDIM);
  gemm_bias<true ><<<grd, blk, 0, stream>>>(H1, W2, b2, H2,  NT, 1024, 1024);
  gemm_bias<false><<<grd, blk, 0, stream>>>(H2, W3, b3, LOG, NT, GC,   1024);
  // offsets MLP hidden layers (reuse H1/H2)
  gemm_bias<true ><<<grd, blk, 0, stream>>>(X,  O1, ob1, H1, NT, 1024, EDIM);
  gemm_bias<true ><<<grd, blk, 0, stream>>>(H1, O2, ob2, H2, NT, 1024, 1024);

  // categorical sampling: NT*G waves
  sample_kernel<<<(NT * G) / 4, 256, 0, stream>>>(LOG, centers);

  // fused gather + decode + a_hat + loss partials
  token_kernel<<<NT, 128, 0, stream>>>(H2, O3, ob3, LOG, centers, bins,
                                       codebook, Wd, bd, action,
                                       out, off_partial, focal_partial);

  final_reduce<<<1, 256, 0, stream>>>(off_partial, focal_partial, out + NT * WA);
}

// Round 7
// 591.200 us; speedup vs baseline: 1.4118x; 1.4118x over previous
//
#include <hip/hip_runtime.h>
#include <hip/hip_bf16.h>
#include <stdint.h>

#define NT   1280
#define EDIM 1024
#define G    2
#define C    512
#define D    64
#define WA   70
#define GC   1024            // G*C
#define O3W  71680           // G*C*WA
#define TC   7               // tokens per chunk in offsets_gather

// ---------------- JAX threefry2x32 (exact port) ----------------
__device__ __forceinline__ uint32_t rotl32(uint32_t v, int r) {
  return (v << r) | (v >> (32 - r));
}

__device__ __forceinline__ void threefry2x32(uint32_t k0, uint32_t k1,
                                             uint32_t& x0, uint32_t& x1) {
  const uint32_t ks2 = k0 ^ k1 ^ 0x1BD11BDAu;
  x0 += k0; x1 += k1;
#define TF_R(r) { x0 += x1; x1 = rotl32(x1, (r)); x1 ^= x0; }
  TF_R(13) TF_R(15) TF_R(26) TF_R(6)
  x0 += k1;  x1 += ks2 + 1u;
  TF_R(17) TF_R(29) TF_R(16) TF_R(24)
  x0 += ks2; x1 += k0 + 2u;
  TF_R(13) TF_R(15) TF_R(26) TF_R(6)
  x0 += k0;  x1 += k1 + 3u;
  TF_R(17) TF_R(29) TF_R(16) TF_R(24)
  x0 += k1;  x1 += ks2 + 4u;
  TF_R(13) TF_R(15) TF_R(26) TF_R(6)
  x0 += ks2; x1 += k0 + 5u;
#undef TF_R
}

// gumbel for flat index into (NT,G,C), key=(0,42), partitionable threefry:
// counter u64 idx -> (hi=0, lo=idx); 32-bit bits = out_x0 ^ out_x1.
__device__ __forceinline__ float jax_gumbel(uint32_t idx) {
  uint32_t x0 = 0u, x1 = idx;
  threefry2x32(0u, 42u, x0, x1);
  uint32_t bits = x0 ^ x1;
  float u = __uint_as_float((bits >> 9) | 0x3F800000u) - 1.0f;
  u = fmaxf(u, 1.17549435e-38f);
  return -logf(-logf(u));
}

// ---------------- f32 tiled GEMM: C = act(A@B + bias) ----------------
template<bool RELU>
__global__ __launch_bounds__(256) void gemm_bias(
    const float* __restrict__ A, const float* __restrict__ B,
    const float* __restrict__ bias, float* __restrict__ Cout,
    int M, int N, int K) {
  __shared__ float As[16][64];   // [k][m]
  __shared__ float Bs[16][64];   // [k][n]
  const int tid = threadIdx.x;
  const int row0 = blockIdx.y * 64, col0 = blockIdx.x * 64;
  const int tx = tid & 15, ty = tid >> 4;
  const int arow = tid >> 2, acol4 = (tid & 3) * 4;
  const int brow = tid >> 4, bcol4 = (tid & 15) * 4;

  float acc[4][4] = {};
  for (int k0 = 0; k0 < K; k0 += 16) {
    float4 av = *(const float4*)&A[(size_t)(row0 + arow) * K + k0 + acol4];
    As[acol4 + 0][arow] = av.x; As[acol4 + 1][arow] = av.y;
    As[acol4 + 2][arow] = av.z; As[acol4 + 3][arow] = av.w;
    float4 bv = *(const float4*)&B[(size_t)(k0 + brow) * N + col0 + bcol4];
    *(float4*)&Bs[brow][bcol4] = bv;
    __syncthreads();
#pragma unroll
    for (int kk = 0; kk < 16; ++kk) {
      float4 a4 = *(const float4*)&As[kk][ty * 4];
      float4 b4 = *(const float4*)&Bs[kk][tx * 4];
      float a[4] = {a4.x, a4.y, a4.z, a4.w};
      float b[4] = {b4.x, b4.y, b4.z, b4.w};
#pragma unroll
      for (int i = 0; i < 4; ++i)
#pragma unroll
        for (int j = 0; j < 4; ++j)
          acc[i][j] = fmaf(a[i], b[j], acc[i][j]);
    }
    __syncthreads();
  }
#pragma unroll
  for (int i = 0; i < 4; ++i) {
    int r = row0 + ty * 4 + i;
#pragma unroll
    for (int j = 0; j < 4; ++j) {
      int c = col0 + tx * 4 + j;
      float v = acc[i][j] + bias[c];
      if (RELU) v = fmaxf(v, 0.0f);
      Cout[(size_t)r * N + c] = v;
    }
  }
}

// ---------------- categorical sampling (one wave per (t,g)) ----------------
__global__ __launch_bounds__(256) void sample_kernel(
    const float* __restrict__ logits,   // (NT, GC)
    int* __restrict__ centers) {        // (NT*G)
  const int wid = (int)((blockIdx.x * blockDim.x + threadIdx.x) >> 6); // t*G+g
  const int lane = threadIdx.x & 63;
  if (wid >= NT * G) return;
  const float* lrow = logits + (size_t)wid * C;
  float bestv = -INFINITY; int bestc = 0;
  for (int i = 0; i < 8; ++i) {
    int c = lane + 64 * i;
    float v = jax_gumbel((uint32_t)(wid * C + c)) + lrow[c];
    if (v > bestv) { bestv = v; bestc = c; }
  }
  for (int off = 32; off > 0; off >>= 1) {
    float ov = __shfl_xor(bestv, off);
    int   oc = __shfl_xor(bestc, off);
    if (ov > bestv || (ov == bestv && oc < bestc)) { bestv = ov; bestc = oc; }
  }
  if (lane == 0) centers[wid] = bestc;
}

// ---------------- column lists: counts + token lists ----------------
__global__ __launch_bounds__(256) void zero_counts(int* __restrict__ counts) {
  int i = blockIdx.x * 256 + threadIdx.x;
  if (i < GC) counts[i] = 0;
}

__global__ __launch_bounds__(256) void build_lists(
    const int* __restrict__ centers, int* __restrict__ counts,
    int* __restrict__ tlist) {
  int i = blockIdx.x * 256 + threadIdx.x;   // t*G+g
  if (i >= NT * G) return;
  int t = i >> 1, g = i & 1;
  int gc = g * C + centers[i];
  int slot = atomicAdd(&counts[gc], 1);     // list order irrelevant -> deterministic output
  tlist[(size_t)gc * NT + slot] = t;
}

// ---------------- column-centric offsets gather ----------------
// One block per (g,c) column. Streams the 1024xWA O3 column block through LDS
// exactly once per token-chunk; computes og for all tokens that sampled it.
__global__ __launch_bounds__(512) void offsets_gather(
    const float* __restrict__ HO2,    // (NT,1024)
    const float* __restrict__ O3,     // (1024, O3W)
    const float* __restrict__ ob3,    // (O3W)
    const int*   __restrict__ counts, // (GC)
    const int*   __restrict__ tlist,  // (GC, NT)
    float* __restrict__ og) {         // (NT, G, WA)
  const int gc = blockIdx.x;
  const int n = counts[gc];
  if (n == 0) return;
  const int tid = threadIdx.x;
  const int g = gc >> 9;                    // gc / C
  const size_t base = (size_t)gc * WA;

  __shared__ float h_l[TC][1024];
  __shared__ float o3_l[64][WA];

  const int i = tid / WA;                   // token-in-chunk (0..7)
  const int a = tid - i * WA;               // action dim (0..69)

  for (int cb = 0; cb < n; cb += TC) {
    const int nn = min(TC, n - cb);
    // stage h rows for this chunk (coalesced float4)
    for (int j = 0; j < nn; ++j) {
      const int t = tlist[(size_t)gc * NT + cb + j];
      if (tid < 256)
        ((float4*)h_l[j])[tid] = ((const float4*)(HO2 + (size_t)t * 1024))[tid];
    }
    const bool act = (i < nn);
    float acc = 0.0f;
    for (int k0 = 0; k0 < 1024; k0 += 64) {
      // stage O3 k-tile (rows contiguous, ~coalesced)
      for (int f = tid; f < 64 * WA; f += 512) {
        const int kk = f / WA, aa = f - kk * WA;
        o3_l[kk][aa] = O3[(size_t)(k0 + kk) * O3W + base + aa];
      }
      __syncthreads();
      if (act) {
#pragma unroll 8
        for (int kk = 0; kk < 64; ++kk)
          acc = fmaf(h_l[i][k0 + kk], o3_l[kk][a], acc);
      }
      __syncthreads();
    }
    if (act) {
      const int t = tlist[(size_t)gc * NT + cb + i];
      og[((size_t)t * G + g) * WA + a] = acc + ob3[base + a];
    }
    __syncthreads();   // protect h_l before next chunk re-stage
  }
}

// ---------------- per-token: decode, a_hat, loss partials ----------------
__global__ __launch_bounds__(128) void token_final(
    const float* __restrict__ og,       // (NT,G,WA)
    const float* __restrict__ logits,   // (NT, GC)
    const int*   __restrict__ centers,  // (NT*G)
    const int*   __restrict__ bins,     // (NT*G)
    const float* __restrict__ codebook, // (G,C,D)
    const float* __restrict__ Wd,       // (128,70)
    const float* __restrict__ bd,       // (70)
    const float* __restrict__ action,   // (NT,70)
    float* __restrict__ a_hat,          // (NT,70) -> d_out
    float* __restrict__ off_partial,    // (NT)
    float* __restrict__ focal_partial) {// (2*NT), [g*NT+t]
  const int t = blockIdx.x;
  const int tid = threadIdx.x;
  const int lane = tid & 63;
  const int g = tid >> 6;

  __shared__ float dec_in[128];
  __shared__ float absdiff[WA];

  const int c = centers[t * G + g];
  dec_in[tid] = codebook[((size_t)(g * C + c)) * D + lane];
  __syncthreads();

  if (tid < WA) {
    float dv = bd[tid];
#pragma unroll 8
    for (int j = 0; j < 128; ++j) dv = fmaf(dec_in[j], Wd[j * WA + tid], dv);
    float ah = dv + og[((size_t)t * G + 0) * WA + tid]
                  + og[((size_t)t * G + 1) * WA + tid];
    a_hat[(size_t)t * WA + tid] = ah;
    absdiff[tid] = fabsf(action[(size_t)t * WA + tid] - ah);
  }
  __syncthreads();
  if (tid == 0) {
    float s = 0.0f;
    for (int a = 0; a < WA; ++a) s += absdiff[a];
    off_partial[t] = s;
  }

  // focal partial for group g (wave-wide over 512 logits)
  const float* lrow = logits + (size_t)t * GC + g * C;
  float lv[8], mx = -INFINITY;
#pragma unroll
  for (int i = 0; i < 8; ++i) { lv[i] = lrow[lane + 64 * i]; mx = fmaxf(mx, lv[i]); }
  for (int off = 32; off > 0; off >>= 1) mx = fmaxf(mx, __shfl_xor(mx, off));
  float se = 0.0f;
#pragma unroll
  for (int i = 0; i < 8; ++i) se += expf(lv[i] - mx);
  for (int off = 32; off > 0; off >>= 1) se += __shfl_xor(se, off);
  if (lane == 0) {
    int target = bins[t * G + g];
    float logpt = lrow[target] - mx - logf(se);
    float pt = expf(logpt);
    float om = 1.0f - pt;
    focal_partial[g * NT + t] = -om * om * logpt;
  }
}

// ---------------- final deterministic reduction ----------------
__global__ __launch_bounds__(256) void final_reduce(
    const float* __restrict__ off_partial,
    const float* __restrict__ focal_partial,
    float* __restrict__ out_loss) {
  const int tid = threadIdx.x;
  double s_off = 0.0, s_f0 = 0.0, s_f1 = 0.0;
  for (int t = tid; t < NT; t += 256) {
    s_off += (double)off_partial[t];
    s_f0  += (double)focal_partial[t];
    s_f1  += (double)focal_partial[NT + t];
  }
  __shared__ double sh0[256], sh1[256], sh2[256];
  sh0[tid] = s_off; sh1[tid] = s_f0; sh2[tid] = s_f1;
  __syncthreads();
  for (int s = 128; s > 0; s >>= 1) {
    if (tid < s) { sh0[tid] += sh0[tid + s]; sh1[tid] += sh1[tid + s]; sh2[tid] += sh2[tid + s]; }
    __syncthreads();
  }
  if (tid == 0) {
    double offset_loss = sh0[0] / (double)(NT * WA);
    double cbet = 5.0 * (sh1[0] / (double)NT) + 0.5 * (sh2[0] / (double)NT);
    out_loss[0] = (float)(cbet + 100.0 * offset_loss);
  }
}

// ---------------- launch ----------------
extern "C" void kernel_launch(void* const* d_in, const int* in_sizes, int n_in,
                              void* d_out, int out_size, void* d_ws, size_t ws_size,
                              hipStream_t stream) {
  const float* X       = (const float*)d_in[0];
  const float* action  = (const float*)d_in[1];
  const int*   bins    = (const int*)  d_in[2];
  const float* W1 = (const float*)d_in[3];  const float* b1  = (const float*)d_in[4];
  const float* W2 = (const float*)d_in[5];  const float* b2  = (const float*)d_in[6];
  const float* W3 = (const float*)d_in[7];  const float* b3  = (const float*)d_in[8];
  const float* O1 = (const float*)d_in[9];  const float* ob1 = (const float*)d_in[10];
  const float* O2 = (const float*)d_in[11]; const float* ob2 = (const float*)d_in[12];
  const float* O3 = (const float*)d_in[13]; const float* ob3 = (const float*)d_in[14];
  const float* codebook = (const float*)d_in[15];
  const float* Wd = (const float*)d_in[16]; const float* bd  = (const float*)d_in[17];
  float* out = (float*)d_out;

  // workspace layout (~22 MB)
  float* H1  = (float*)d_ws;                      // NT*1024
  float* H2  = H1 + (size_t)NT * 1024;            // NT*1024
  float* LOG = H2 + (size_t)NT * 1024;            // NT*1024
  int*   centers       = (int*)(LOG + (size_t)NT * 1024);  // NT*G
  int*   counts        = centers + NT * G;                 // GC
  int*   tlist         = counts + GC;                      // GC*NT
  float* og            = (float*)(tlist + (size_t)GC * NT);// NT*G*WA
  float* off_partial   = og + (size_t)NT * G * WA;         // NT
  float* focal_partial = off_partial + NT;                 // 2*NT

  dim3 blk(256);
  dim3 grd(GC / 64, NT / 64);   // (16, 20)

  // logits MLP
  gemm_bias<true ><<<grd, blk, 0, stream>>>(X,  W1, b1, H1,  NT, 1024, EDIM);
  gemm_bias<true ><<<grd, blk, 0, stream>>>(H1, W2, b2, H2,  NT, 1024, 1024);
  gemm_bias<false><<<grd, blk, 0, stream>>>(H2, W3, b3, LOG, NT, GC,   1024);
  // offsets MLP hidden layers (reuse H1/H2)
  gemm_bias<true ><<<grd, blk, 0, stream>>>(X,  O1, ob1, H1, NT, 1024, EDIM);
  gemm_bias<true ><<<grd, blk, 0, stream>>>(H1, O2, ob2, H2, NT, 1024, 1024);

  // categorical sampling: NT*G waves
  sample_kernel<<<(NT * G) / 4, 256, 0, stream>>>(LOG, centers);

  // build per-column token lists
  zero_counts<<<GC / 256, 256, 0, stream>>>(counts);
  build_lists<<<(NT * G + 255) / 256, 256, 0, stream>>>(centers, counts, tlist);

  // column-centric gathered-offsets GEMM
  offsets_gather<<<GC, 512, 0, stream>>>(H2, O3, ob3, counts, tlist, og);

  // per-token decode + a_hat + loss partials
  token_final<<<NT, 128, 0, stream>>>(og, LOG, centers, bins, codebook,
                                      Wd, bd, action,
                                      out, off_partial, focal_partial);

  final_reduce<<<1, 256, 0, stream>>>(off_partial, focal_partial, out + NT * WA);
}